// Round 5
// baseline (433.055 us; speedup 1.0000x reference)
//
#include <hip/hip_runtime.h>
#include <hip/hip_bf16.h>

typedef __attribute__((ext_vector_type(8))) short bf16x8;
typedef __attribute__((ext_vector_type(4))) float f32x4;
typedef __attribute__((ext_vector_type(16))) float f32x16;

#define DIN 24
#define DOUT 47
#define SPD (DOUT*DOUT)
#define CIN 32
#define COUT 64
#define SP_IN 13824
#define SP_OUT 103823
#define GROUPS 8
#define WPK_OFF 512
#define LROW 40          // elems per (plane,iw) row: 32 ci + 8 pad (80B, 16B-aligned)
#define PLANE 1000       // 25 rows * LROW  (iw 0..23 data, iw=24 zero row)

__device__ __forceinline__ unsigned short f2bf(float v) {
    __hip_bfloat16 h = __float2bfloat16(v);
    return *(const unsigned short*)&h;
}

__device__ __forceinline__ float hswish(float z) {
    float c = fminf(fmaxf(z + 3.f, 0.f), 6.f);
    return z * c * (1.f / 6.f);
}

// wpk[tap][cohalf][cihalf][lane][j]: A-frag for 32x32x16 bf16.
// co = cohalf*32 + (lane&31), ci = cihalf*16 + (lane>>5)*8 + j
__global__ __launch_bounds__(256)
void repack_w(const float* __restrict__ w, unsigned short* __restrict__ wpk)
{
    int i = blockIdx.x * 256 + threadIdx.x;
    if (i >= 27 * 2 * 2 * 64 * 8) return;
    int j = i & 7;
    int lane = (i >> 3) & 63;
    int cih = (i >> 9) & 1;
    int ch = (i >> 10) & 1;
    int tap = i >> 11;
    int kw = tap % 3, kh = (tap / 3) % 3, kd = tap / 9;
    int co = ch * 32 + (lane & 31);
    int ci = cih * 16 + ((lane >> 5) << 3) + j;
    wpk[i] = f2bf(w[(((co * CIN + ci) * 3 + kd) * 3 + kh) * 3 + kw]);
}

// One class: fixed od (parity via NKD2), fixed oh-parity OHP.
// NKD2=0 -> even od (kd=1, idl=0); NKD2=1 -> odd od (kd=0 idl=1, kd=2 idl=0).
template<int NKD2, int OHP>
__device__ __forceinline__ void do_class(
    const unsigned short* __restrict__ xs,
    const unsigned short* __restrict__ wA,   // wpk + lane*8
    int ch, int ihb0,
    const int (&offE)[2], const int (&offO)[2],
    int od, int ohBase, int ohsel, int ph, int kgrp,
    const f32x4 (&bq)[4],
    float* __restrict__ yb0,
    float (&s1g)[4], float (&s2g)[4])
{
    const int oh = ohBase + OHP + 2 * ohsel;
    const bool vrow = (oh < DOUT);

    #pragma unroll
    for (int t = 0; t < 2; ++t) {
        f32x16 accE, accO;
        #pragma unroll
        for (int r = 0; r < 16; ++r) { accE[r] = 0.f; accO[r] = 0.f; }

        #pragma unroll
        for (int cih = 0; cih < 2; ++cih) {
            const int cio = cih * 16;
            #pragma unroll
            for (int dk = 0; dk < (NKD2 ? 2 : 1); ++dk) {
                const int kd  = NKD2 ? (dk ? 2 : 0) : 1;
                const int idl = NKD2 ? (dk ? 0 : 1) : 0;
                #pragma unroll
                for (int khi = 0; khi < (OHP ? 2 : 1); ++khi) {
                    const int kh = OHP ? (khi ? 2 : 0) : 1;
                    const int dh = (OHP && kh == 0) ? 1 : 0;
                    const int pbase = (idl * 5 + ihb0 + dh) * PLANE + cio;
                    const bf16x8 bE = *(const bf16x8*)&xs[pbase + offE[t]];
                    const bf16x8 bO = *(const bf16x8*)&xs[pbase + offO[t]];
                    const int tb = (kd * 3 + kh) * 3;
                    const bf16x8 a1 = *(const bf16x8*)&wA[(((tb + 1) * 2 + ch) * 2 + cih) * 512];
                    const bf16x8 a0 = *(const bf16x8*)&wA[(((tb + 0) * 2 + ch) * 2 + cih) * 512];
                    const bf16x8 a2 = *(const bf16x8*)&wA[(((tb + 2) * 2 + ch) * 2 + cih) * 512];
                    accE = __builtin_amdgcn_mfma_f32_32x32x16_bf16(a1, bE, accE, 0, 0, 0);
                    accO = __builtin_amdgcn_mfma_f32_32x32x16_bf16(a0, bO, accO, 0, 0, 0);
                    accO = __builtin_amdgcn_mfma_f32_32x32x16_bf16(a2, bE, accO, 0, 0, 0);
                }
            }
        }

        const int owE = 32 * t + 2 * ph;
        const bool vE = vrow && (owE < DOUT);
        const bool vO = vrow && (owE + 1 < DOUT);
        float* yr = yb0 + (size_t)od * SPD + (size_t)oh * DOUT + owE;
        #pragma unroll
        for (int reg = 0; reg < 16; ++reg) {
            const int q = reg >> 2;
            const int co_r = (reg & 3) + 8 * q + 4 * kgrp;
            const float bb = bq[q][reg & 3];
            float e = accE[reg] + bb;
            float o = accO[reg] + bb;
            float se = e / (1.f + __expf(-e));
            float so = o / (1.f + __expf(-o));
            if (vE) { yr[(size_t)co_r * SP_OUT]     = se; s1g[q] += se; s2g[q] += se * se; }
            if (vO) { yr[(size_t)co_r * SP_OUT + 1] = so; s1g[q] += so; s2g[q] += so * so; }
        }
    }
}

__global__ __launch_bounds__(256, 4)
void conv_mfma(const float* __restrict__ x, const unsigned short* __restrict__ wpk,
               const float* __restrict__ bias, float* __restrict__ y,
               float* __restrict__ stats)
{
    __shared__ unsigned short xs[10 * PLANE];   // 20000 B

    const int bx = blockIdx.x;                  // 24 od-pairs * 6 oh-slabs
    const int u = bx / 6;
    const int s = bx - u * 6;
    const int n = blockIdx.z;
    const int tid = threadIdx.x;

    // ---- stage 10 planes (idl 0..1, ihl 0..4) x 24 iw x 32 ci, fp32->bf16 transpose
    const float* xb = x + (size_t)n * (CIN * SP_IN);
    for (int i = tid; i < 1920; i += 256) {
        int j = i % 6;
        int r = i / 6;
        int ci = r & 31;
        int pl = r >> 5;
        int ihl = pl % 5, idl = pl / 5;
        int id = min(u + idl, 23);
        int ih = min(4 * s + ihl, 23);
        const float4 v = *(const float4*)(xb + ci * SP_IN + (id * DIN + ih) * DIN + 4 * j);
        int base = pl * PLANE + (4 * j) * LROW + ci;
        xs[base + 0 * LROW] = f2bf(v.x);
        xs[base + 1 * LROW] = f2bf(v.y);
        xs[base + 2 * LROW] = f2bf(v.z);
        xs[base + 3 * LROW] = f2bf(v.w);
    }
    for (int i = tid; i < 320; i += 256) {      // zero row iw=24 per plane
        int ci = i & 31, pl = i >> 5;
        xs[pl * PLANE + 24 * LROW + ci] = 0;
    }
    __syncthreads();

    const int lane = tid & 63;
    const int wv = tid >> 6;
    const int ch = wv & 1;                      // co half (32 co)
    const int ohh = wv >> 1;                    // oh half (4 oh)
    const int col = lane & 31;
    const int ph = col & 15;                    // ow-pair index within tile
    const int ohsel = col >> 4;
    const int kgrp = lane >> 5;                 // k sub-group (8 ci)
    const int ihb0 = 2 * ohh + ohsel;

    int offE[2], offO[2];
    #pragma unroll
    for (int t = 0; t < 2; ++t) {
        int c = 16 * t + ph;
        offE[t] = (c <= 23 ? c : 24) * LROW + kgrp * 8;
        offO[t] = (c <= 22 ? c + 1 : 24) * LROW + kgrp * 8;
    }

    f32x4 bq[4];
    #pragma unroll
    for (int q = 0; q < 4; ++q)
        bq[q] = *(const f32x4*)&bias[ch * 32 + 8 * q + 4 * kgrp];

    const unsigned short* wA = wpk + (size_t)lane * 8;
    float* yb0 = y + ((size_t)n * COUT + ch * 32) * SP_OUT;
    float s1g[4] = {0.f, 0.f, 0.f, 0.f};
    float s2g[4] = {0.f, 0.f, 0.f, 0.f};
    const int od0 = 2 * u;
    const int ohBase = 8 * s + 4 * ohh;

    do_class<0, 0>(xs, wA, ch, ihb0, offE, offO, od0, ohBase, ohsel, ph, kgrp, bq, yb0, s1g, s2g);
    do_class<0, 1>(xs, wA, ch, ihb0, offE, offO, od0, ohBase, ohsel, ph, kgrp, bq, yb0, s1g, s2g);
    if (od0 + 1 < DOUT) {
        do_class<1, 0>(xs, wA, ch, ihb0, offE, offO, od0 + 1, ohBase, ohsel, ph, kgrp, bq, yb0, s1g, s2g);
        do_class<1, 1>(xs, wA, ch, ihb0, offE, offO, od0 + 1, ohBase, ohsel, ph, kgrp, bq, yb0, s1g, s2g);
    }

    // stats: group g = ch*4 + q  (co = ch*32 + 8q + [0,8))
    #pragma unroll
    for (int q = 0; q < 4; ++q) {
        float a = s1g[q], b = s2g[q];
        #pragma unroll
        for (int off = 32; off; off >>= 1) {
            a += __shfl_down(a, off);
            b += __shfl_down(b, off);
        }
        if (lane == 0) {
            const int g = ch * 4 + q;
            atomicAdd(&stats[(n * GROUPS + g) * 2 + 0], a);
            atomicAdd(&stats[(n * GROUPS + g) * 2 + 1], b);
        }
    }
}

__global__ __launch_bounds__(256)
void norm_hswish(float* __restrict__ y, const float* __restrict__ stats)
{
    const int total4 = (8 * COUT * SP_OUT) / 4;
    const int grp4 = (8 * SP_OUT) / 4;
    const float inv_cnt = 1.0f / (8.0f * (float)SP_OUT);
    float4* p = (float4*)y;
    int idx = blockIdx.x * 256 + threadIdx.x;
    const int stride = gridDim.x * 256;
    for (int i = idx; i < total4; i += stride) {
        const int ng = i / grp4;
        const float m1 = stats[ng * 2 + 0] * inv_cnt;
        const float m2 = stats[ng * 2 + 1] * inv_cnt;
        const float var = m2 - m1 * m1;
        const float rstd = rsqrtf(var + 1e-5f);
        float4 v = p[i];
        v.x = hswish((v.x - m1) * rstd);
        v.y = hswish((v.y - m1) * rstd);
        v.z = hswish((v.z - m1) * rstd);
        v.w = hswish((v.w - m1) * rstd);
        p[i] = v;
    }
}

extern "C" void kernel_launch(void* const* d_in, const int* in_sizes, int n_in,
                              void* d_out, int out_size, void* d_ws, size_t ws_size,
                              hipStream_t stream)
{
    const float* x    = (const float*)d_in[0];
    const float* w    = (const float*)d_in[1];
    const float* bias = (const float*)d_in[2];
    float* y     = (float*)d_out;
    float* stats = (float*)d_ws;
    unsigned short* wpk = (unsigned short*)((char*)d_ws + WPK_OFF);

    hipMemsetAsync(d_ws, 0, 512, stream);
    repack_w<<<216, 256, 0, stream>>>(w, wpk);

    dim3 grid(24 * 6, 1, 8);
    conv_mfma<<<grid, 256, 0, stream>>>(x, wpk, bias, y, stats);

    norm_hswish<<<2048, 256, 0, stream>>>(y, stats);
}

// Round 6
// 345.730 us; speedup vs baseline: 1.2526x; 1.2526x over previous
//
#include <hip/hip_runtime.h>
#include <hip/hip_bf16.h>

typedef __attribute__((ext_vector_type(8))) short bf16x8;
typedef __attribute__((ext_vector_type(4))) float f32x4;

#define DIN 24
#define DOUT 47
#define SPD (DOUT*DOUT)
#define CIN 32
#define COUT 64
#define SP_IN 13824
#define SP_OUT 103823
#define GROUPS 8
#define WPK_OFF 512
#define Y_OFF 131072
#define LROW 40          // elems per (plane,iw) row: 32 ci + 8 pad (80B, 16B-aligned)
#define PLANE 1000       // 25 rows * LROW (iw 0..23 data, iw=24 zero row)

__device__ __forceinline__ unsigned short f2bf(float v) {
    __hip_bfloat16 h = __float2bfloat16(v);
    return *(const unsigned short*)&h;
}

__device__ __forceinline__ float hswish(float z) {
    float c = fminf(fmaxf(z + 3.f, 0.f), 6.f);
    return z * c * (1.f / 6.f);
}

// wpk[tap][coblk][lane][j]: A-frag bf16, co = coblk*16+(lane&15), ci = (lane>>4)*8+j
__global__ __launch_bounds__(256)
void repack_w(const float* __restrict__ w, unsigned short* __restrict__ wpk)
{
    int i = blockIdx.x * 256 + threadIdx.x;
    if (i >= 27 * 4 * 64 * 8) return;
    int j = i & 7;
    int lane = (i >> 3) & 63;
    int coblk = (i >> 9) & 3;
    int tap = i >> 11;
    int kw = tap % 3, kh = (tap / 3) % 3, kd = tap / 9;
    int co = coblk * 16 + (lane & 15);
    int ci = (lane >> 4) * 8 + j;
    wpk[i] = f2bf(w[(((co * CIN + ci) * 3 + kd) * 3 + kh) * 3 + kw]);
}

// One wave, one parity class (PD,PH): od = 2u+PD, oh = 8s+PH+2f (f=0..3),
// ow = 16w + col (columns = consecutive ow; parity-invalid (col,kw) -> zero row).
template<int PD, int PH, bool B16>
__device__ __forceinline__ void wave_work(
    const unsigned short* __restrict__ wpk,
    const unsigned short* __restrict__ xs,
    const float* __restrict__ bias,
    char* __restrict__ ybase,            // pre-offset to batch n
    float* __restrict__ stats,
    int n, int u, int s, int cb, int lane)
{
    const int od = 2 * u + PD;
    if (od >= DOUT) return;
    constexpr int NKD = PD ? 2 : 1;
    constexpr int NKH = PH ? 2 : 1;
    constexpr int NT = NKD * NKH * 3;

    const int col = lane & 15;
    const int kg = lane >> 4;

    // ---- preload A-frags (once) ----
    bf16x8 af[NT];
    #pragma unroll
    for (int dk = 0; dk < NKD; ++dk) {
        const int kd = PD ? (dk ? 2 : 0) : 1;
        #pragma unroll
        for (int hk = 0; hk < NKH; ++hk) {
            const int kh = PH ? (hk ? 2 : 0) : 1;
            #pragma unroll
            for (int kw = 0; kw < 3; ++kw) {
                const int tap = (kd * 3 + kh) * 3 + kw;
                af[(dk * NKH + hk) * 3 + kw] =
                    *(const bf16x8*)&wpk[(size_t)((tap * 4 + cb) * 64 + lane) * 8];
            }
        }
    }

    // per-lane B offsets: off[w][kw] (zero row 24 when parity-invalid)
    int off[3][3];
    #pragma unroll
    for (int w = 0; w < 3; ++w)
        #pragma unroll
        for (int kw = 0; kw < 3; ++kw) {
            int num = col + 1 - kw;
            bool pv = (num & 1) == 0;          // parity-valid
            int iw = 8 * w + (num >> 1);       // in [0,24] when pv
            off[w][kw] = (pv ? iw : 24) * LROW + kg * 8;
        }

    const f32x4 bv = *(const f32x4*)&bias[cb * 16 + kg * 4];
    const size_t cob = (size_t)(cb * 16 + kg * 4) * SP_OUT;
    float s1 = 0.f, s2 = 0.f;

    for (int f = 0; f < 4; ++f) {
        const int oh = 8 * s + PH + 2 * f;
        f32x4 a0 = {0,0,0,0}, a1 = {0,0,0,0}, a2 = {0,0,0,0};
        #pragma unroll
        for (int dk = 0; dk < NKD; ++dk) {
            const int idl = PD ? (dk ? 0 : 1) : 0;
            #pragma unroll
            for (int hk = 0; hk < NKH; ++hk) {
                const int dh = PH ? (hk ? 0 : 1) : 0;
                const int pbase = (idl * 5 + f + dh) * PLANE;
                #pragma unroll
                for (int kw = 0; kw < 3; ++kw) {
                    const bf16x8 aa = af[(dk * NKH + hk) * 3 + kw];
                    a0 = __builtin_amdgcn_mfma_f32_16x16x32_bf16(aa, *(const bf16x8*)&xs[pbase + off[0][kw]], a0, 0, 0, 0);
                    a1 = __builtin_amdgcn_mfma_f32_16x16x32_bf16(aa, *(const bf16x8*)&xs[pbase + off[1][kw]], a1, 0, 0, 0);
                    a2 = __builtin_amdgcn_mfma_f32_16x16x32_bf16(aa, *(const bf16x8*)&xs[pbase + off[2][kw]], a2, 0, 0, 0);
                }
            }
        }
        const bool vrow = (oh < DOUT);
        #pragma unroll
        for (int w = 0; w < 3; ++w) {
            const f32x4 A = (w == 0) ? a0 : ((w == 1) ? a1 : a2);
            const int ow = 16 * w + col;
            const bool v = vrow && (ow < DOUT);
            const size_t sp = (size_t)od * SPD + (size_t)oh * DOUT + ow;
            #pragma unroll
            for (int j = 0; j < 4; ++j) {
                float val = A[j] + bv[j];
                float sw = val / (1.f + __expf(-val));
                if (v) {
                    if (B16)
                        ((unsigned short*)ybase)[cob + (size_t)j * SP_OUT + sp] = f2bf(sw);
                    else
                        ((float*)ybase)[cob + (size_t)j * SP_OUT + sp] = sw;
                    s1 += sw;
                    s2 += sw * sw;
                }
            }
        }
    }

    // rows kg<2 -> group 2cb, kg>=2 -> 2cb+1 (lane 0 / lane 32 read the halves)
    #pragma unroll
    for (int o = 16; o; o >>= 1) {
        s1 += __shfl_down(s1, o);
        s2 += __shfl_down(s2, o);
    }
    if ((lane & 31) == 0) {
        const int g = cb * 2 + (lane >> 5);
        atomicAdd(&stats[(n * GROUPS + g) * 2 + 0], s1);
        atomicAdd(&stats[(n * GROUPS + g) * 2 + 1], s2);
    }
}

template<bool B16>
__global__ __launch_bounds__(512, 4)
void conv_mfma(const float* __restrict__ x, const unsigned short* __restrict__ wpk,
               const float* __restrict__ bias, char* __restrict__ yb,
               float* __restrict__ stats)
{
    __shared__ unsigned short xs[10 * PLANE];   // 20000 B

    const int bx = blockIdx.x;                  // 24 od-pairs * 6 oh-slabs
    const int u = bx / 6;
    const int s = bx - u * 6;
    const int by = blockIdx.y;                  // co half
    const int n = blockIdx.z;
    const int tid = threadIdx.x;

    // ---- stage 10 planes (idl 0..1, ihl 0..4) x 24 iw x 32 ci, fp32->bf16 transpose
    const float* xb = x + (size_t)n * (CIN * SP_IN);
    for (int i = tid; i < 1920; i += 512) {
        int j = i % 6;
        int r = i / 6;
        int ci = r & 31;
        int pl = r >> 5;                        // 0..9
        int ihl = pl % 5, idl = pl / 5;
        int id = min(u + idl, 23);
        int ih = min(4 * s + ihl, 23);
        const float4 v = *(const float4*)(xb + ci * SP_IN + (id * DIN + ih) * DIN + 4 * j);
        int base = pl * PLANE + (4 * j) * LROW + ci;
        xs[base + 0 * LROW] = f2bf(v.x);
        xs[base + 1 * LROW] = f2bf(v.y);
        xs[base + 2 * LROW] = f2bf(v.z);
        xs[base + 3 * LROW] = f2bf(v.w);
    }
    for (int i = tid; i < 320; i += 512) {      // zero row iw=24 per plane
        int ci = i & 31, pl = i >> 5;
        xs[pl * PLANE + 24 * LROW + ci] = 0;
    }
    __syncthreads();

    const int lane = tid & 63;
    const int wv = tid >> 6;
    const int pc = wv & 3;                      // parity class
    const int cb = by * 2 + (wv >> 2);          // co block (16 co)
    char* ybase = yb + (size_t)n * COUT * SP_OUT * (B16 ? 2 : 4);

    switch (pc) {
        case 0:  wave_work<0, 0, B16>(wpk, xs, bias, ybase, stats, n, u, s, cb, lane); break;
        case 1:  wave_work<0, 1, B16>(wpk, xs, bias, ybase, stats, n, u, s, cb, lane); break;
        case 2:  wave_work<1, 0, B16>(wpk, xs, bias, ybase, stats, n, u, s, cb, lane); break;
        default: wave_work<1, 1, B16>(wpk, xs, bias, ybase, stats, n, u, s, cb, lane); break;
    }
}

__global__ __launch_bounds__(256)
void norm_bf16(const unsigned short* __restrict__ yb,
               const float* __restrict__ stats, float* __restrict__ out)
{
    const int total8 = 8 * COUT * SP_OUT / 8;   // 6,644,672 packs of 8
    const int grp8 = SP_OUT;                    // packs per (n,g): 8*SP_OUT/8
    const float inv_cnt = 1.0f / (8.0f * (float)SP_OUT);
    int idx = blockIdx.x * 256 + threadIdx.x;
    const int stride = gridDim.x * 256;
    for (int i = idx; i < total8; i += stride) {
        const int ng = i / grp8;
        const float m1 = stats[ng * 2 + 0] * inv_cnt;
        const float m2 = stats[ng * 2 + 1] * inv_cnt;
        const float rstd = rsqrtf(m2 - m1 * m1 + 1e-5f);
        const uint4 v = ((const uint4*)yb)[i];
        float4 o0, o1;
        o0.x = hswish((__uint_as_float((v.x & 0xffffu) << 16) - m1) * rstd);
        o0.y = hswish((__uint_as_float((v.x >> 16) << 16) - m1) * rstd);
        o0.z = hswish((__uint_as_float((v.y & 0xffffu) << 16) - m1) * rstd);
        o0.w = hswish((__uint_as_float((v.y >> 16) << 16) - m1) * rstd);
        o1.x = hswish((__uint_as_float((v.z & 0xffffu) << 16) - m1) * rstd);
        o1.y = hswish((__uint_as_float((v.z >> 16) << 16) - m1) * rstd);
        o1.z = hswish((__uint_as_float((v.w & 0xffffu) << 16) - m1) * rstd);
        o1.w = hswish((__uint_as_float((v.w >> 16) << 16) - m1) * rstd);
        ((float4*)out)[2 * i + 0] = o0;
        ((float4*)out)[2 * i + 1] = o1;
    }
}

__global__ __launch_bounds__(256)
void norm_hswish(float* __restrict__ y, const float* __restrict__ stats)
{
    const int total4 = (8 * COUT * SP_OUT) / 4;
    const int grp4 = (8 * SP_OUT) / 4;
    const float inv_cnt = 1.0f / (8.0f * (float)SP_OUT);
    float4* p = (float4*)y;
    int idx = blockIdx.x * 256 + threadIdx.x;
    const int stride = gridDim.x * 256;
    for (int i = idx; i < total4; i += stride) {
        const int ng = i / grp4;
        const float m1 = stats[ng * 2 + 0] * inv_cnt;
        const float m2 = stats[ng * 2 + 1] * inv_cnt;
        const float rstd = rsqrtf(m2 - m1 * m1 + 1e-5f);
        float4 v = p[i];
        v.x = hswish((v.x - m1) * rstd);
        v.y = hswish((v.y - m1) * rstd);
        v.z = hswish((v.z - m1) * rstd);
        v.w = hswish((v.w - m1) * rstd);
        p[i] = v;
    }
}

extern "C" void kernel_launch(void* const* d_in, const int* in_sizes, int n_in,
                              void* d_out, int out_size, void* d_ws, size_t ws_size,
                              hipStream_t stream)
{
    const float* x    = (const float*)d_in[0];
    const float* w    = (const float*)d_in[1];
    const float* bias = (const float*)d_in[2];
    float* stats = (float*)d_ws;
    unsigned short* wpk = (unsigned short*)((char*)d_ws + WPK_OFF);

    hipMemsetAsync(d_ws, 0, 512, stream);
    repack_w<<<216, 256, 0, stream>>>(w, wpk);

    dim3 grid(24 * 6, 2, 8);
    const size_t need = (size_t)Y_OFF + (size_t)8 * COUT * SP_OUT * 2;
    if (ws_size >= need) {
        char* ybf = (char*)d_ws + Y_OFF;
        conv_mfma<true><<<grid, 512, 0, stream>>>(x, wpk, bias, ybf, stats);
        norm_bf16<<<2048, 256, 0, stream>>>((const unsigned short*)ybf, stats, (float*)d_out);
    } else {
        conv_mfma<false><<<grid, 512, 0, stream>>>(x, wpk, bias, (char*)d_out, stats);
        norm_hswish<<<2048, 256, 0, stream>>>((float*)d_out, stats);
    }
}

// Round 7
// 269.006 us; speedup vs baseline: 1.6098x; 1.2852x over previous
//
#include <hip/hip_runtime.h>
#include <hip/hip_bf16.h>

typedef __attribute__((ext_vector_type(8))) short bf16x8;
typedef __attribute__((ext_vector_type(4))) float f32x4;

#define DIN 24
#define DOUT 47
#define SPD 2209
#define CIN 32
#define COUT 64
#define SP_IN 13824
#define SP_OUT 103823
#define GROUPS 8
#define WPK_OFF 512
#define Y_OFF 131072
#define LROW 40          // elems per (plane,iw) row: 32 ci + 8 pad (80B, 16B-aligned)
#define PLANE 1000       // 25 rows * LROW (iw 0..23 data, iw=24 zero row)

__device__ __forceinline__ unsigned short f2bf(float v) {
    __hip_bfloat16 h = __float2bfloat16(v);
    return *(const unsigned short*)&h;
}

__device__ __forceinline__ float hswish(float z) {
    float c = fminf(fmaxf(z + 3.f, 0.f), 6.f);
    return z * c * (1.f / 6.f);
}

// wpk[tap][coblk][lane][j]: A-frag bf16, co = coblk*16+(lane&15), ci = (lane>>4)*8+j
__global__ __launch_bounds__(256)
void repack_w(const float* __restrict__ w, unsigned short* __restrict__ wpk)
{
    int i = blockIdx.x * 256 + threadIdx.x;
    if (i >= 27 * 4 * 64 * 8) return;
    int j = i & 7;
    int lane = (i >> 3) & 63;
    int coblk = (i >> 9) & 3;
    int tap = i >> 11;
    int kw = tap % 3, kh = (tap / 3) % 3, kd = tap / 9;
    int co = coblk * 16 + (lane & 15);
    int ci = (lane >> 4) * 8 + j;
    wpk[i] = f2bf(w[(((co * CIN + ci) * 3 + kd) * 3 + kh) * 3 + kw]);
}

#define MFMA16(A, B, C) __builtin_amdgcn_mfma_f32_16x16x32_bf16(A, B, C, 0, 0, 0)

template<bool B16>
__global__ __launch_bounds__(512, 4)
void conv_mfma(const float* __restrict__ x, const unsigned short* __restrict__ wpk,
               const float* __restrict__ bias, char* __restrict__ yb,
               float* __restrict__ stats)
{
    __shared__ unsigned short xs[15 * PLANE];   // 30000 B

    const int bx = blockIdx.x;                  // 12 od-slabs * 6 oh-slabs
    const int t = bx / 6;                       // od slab [4t, 4t+4)
    const int s = bx - t * 6;                   // oh slab [8s, 8s+8)
    const int n = blockIdx.z;
    const int tid = threadIdx.x;

    // ---- stage 15 planes (idl 0..2, ihl 0..4) x 24 iw x 32 ci, fp32->bf16 transpose
    // ci-fastest lane map: 32 lanes same j -> ~2-way LDS write conflicts only
    const float* xb = x + (size_t)n * (CIN * SP_IN);
    for (int i = tid; i < 2880; i += 512) {
        int ci = i & 31;
        int rest = i >> 5;                      // 0..89
        int j = rest % 6;
        int pl = rest / 6;                      // 0..14
        int ihl = pl % 5, idl = pl / 5;
        int id = min(2 * t + idl, 23);
        int ih = min(4 * s + ihl, 23);
        const float4 v = *(const float4*)(xb + ci * SP_IN + (id * DIN + ih) * DIN + 4 * j);
        int base = pl * PLANE + (4 * j) * LROW + ci;
        xs[base + 0 * LROW] = f2bf(v.x);
        xs[base + 1 * LROW] = f2bf(v.y);
        xs[base + 2 * LROW] = f2bf(v.z);
        xs[base + 3 * LROW] = f2bf(v.w);
    }
    for (int i = tid; i < 480; i += 512) {      // zero row iw=24 per plane
        xs[(i >> 5) * PLANE + 24 * LROW + (i & 31)] = 0;
    }
    __syncthreads();

    const int lane = tid & 63;
    const int wv = tid >> 6;
    const int cb = wv & 3;                      // co block (16 co)
    const int hh = wv >> 2;                     // oh half (4 rows)
    const int col = lane & 15;
    const int kg = lane >> 4;

    // ---- preload all 27 A-frags once (L2-resident wpk) ----
    bf16x8 af[3][3][3];
    #pragma unroll
    for (int kd = 0; kd < 3; ++kd)
        #pragma unroll
        for (int kh = 0; kh < 3; ++kh)
            #pragma unroll
            for (int kw = 0; kw < 3; ++kw) {
                const int tap = (kd * 3 + kh) * 3 + kw;
                af[kd][kh][kw] =
                    *(const bf16x8*)&wpk[(size_t)((tap * 4 + cb) * 64 + lane) * 8];
            }

    // per-lane B row offsets: zero row 24 when (col,kw) parity-invalid
    int off[3][3];
    #pragma unroll
    for (int w = 0; w < 3; ++w)
        #pragma unroll
        for (int kw = 0; kw < 3; ++kw) {
            int num = col + 1 - kw;
            bool pv = ((num & 1) == 0);
            int iw = 8 * w + (num >> 1);
            off[w][kw] = ((pv && iw <= 24) ? iw : 24) * LROW + kg * 8;
        }

    const f32x4 bv = *(const f32x4*)&bias[cb * 16 + kg * 4];
    const size_t cob = ((size_t)n * COUT + cb * 16 + kg * 4) * SP_OUT;
    float s1 = 0.f, s2 = 0.f;

    auto strow = [&](const f32x4 (&A)[3], int od, int oh) {
        const size_t rb = cob + (size_t)od * SPD + (size_t)oh * DOUT;
        #pragma unroll
        for (int w = 0; w < 3; ++w) {
            const int ow = 16 * w + col;
            const bool v = (ow < DOUT);
            #pragma unroll
            for (int j = 0; j < 4; ++j) {
                float val = A[w][j] + bv[j];
                float sw = val / (1.f + __expf(-val));
                if (v) {
                    if (B16)
                        ((unsigned short*)yb)[rb + (size_t)j * SP_OUT + ow] = f2bf(sw);
                    else
                        ((float*)yb)[rb + (size_t)j * SP_OUT + ow] = sw;
                    s1 += sw;
                    s2 += sw * sw;
                }
            }
        }
    };

    #pragma unroll
    for (int e = 0; e < 2; ++e) {
        const int od0 = 4 * t + 2 * e;          // even od, always valid
        const bool odOv = (od0 + 1 < DOUT);
        #pragma unroll
        for (int f = 0; f < 2; ++f) {
            const int bh = 2 * hh + f;
            const int ohE = 8 * s + 2 * bh;     // even oh, always valid
            const int ohO = ohE + 1;
            const bool ohOv = (ohO < DOUT);
            // planes: P00 (kd in {1,2}, kh in {1,2}); P01 (kh=0); P10 (kd=0); P11 (both)
            const int p00 = (e * 5 + bh) * PLANE;
            const int p01 = p00 + PLANE;
            const int p10 = p00 + 5 * PLANE;
            const int p11 = p10 + PLANE;

            f32x4 aEE[3], aEO[3], aOE[3], aOO[3];
            #pragma unroll
            for (int w = 0; w < 3; ++w) {
                aEE[w] = (f32x4){0.f, 0.f, 0.f, 0.f};
                aEO[w] = (f32x4){0.f, 0.f, 0.f, 0.f};
                aOE[w] = (f32x4){0.f, 0.f, 0.f, 0.f};
                aOO[w] = (f32x4){0.f, 0.f, 0.f, 0.f};
            }

            #pragma unroll
            for (int kw = 0; kw < 3; ++kw) {
                #pragma unroll
                for (int w = 0; w < 3; ++w) {
                    const int o = off[w][kw];
                    const bf16x8 b0 = *(const bf16x8*)&xs[p00 + o];
                    aEE[w] = MFMA16(af[1][1][kw], b0, aEE[w]);
                    aEO[w] = MFMA16(af[1][2][kw], b0, aEO[w]);
                    aOE[w] = MFMA16(af[2][1][kw], b0, aOE[w]);
                    aOO[w] = MFMA16(af[2][2][kw], b0, aOO[w]);
                    const bf16x8 b1 = *(const bf16x8*)&xs[p01 + o];
                    aEO[w] = MFMA16(af[1][0][kw], b1, aEO[w]);
                    aOO[w] = MFMA16(af[2][0][kw], b1, aOO[w]);
                    const bf16x8 b2 = *(const bf16x8*)&xs[p10 + o];
                    aOE[w] = MFMA16(af[0][1][kw], b2, aOE[w]);
                    aOO[w] = MFMA16(af[0][2][kw], b2, aOO[w]);
                    const bf16x8 b3 = *(const bf16x8*)&xs[p11 + o];
                    aOO[w] = MFMA16(af[0][0][kw], b3, aOO[w]);
                }
            }

            strow(aEE, od0, ohE);
            if (ohOv) strow(aEO, od0, ohO);
            if (odOv) strow(aOE, od0 + 1, ohE);
            if (odOv && ohOv) strow(aOO, od0 + 1, ohO);
        }
    }

    // stats: lanes 0-31 (kg 0,1) -> group 2cb; lanes 32-63 -> 2cb+1
    #pragma unroll
    for (int o = 16; o; o >>= 1) {
        s1 += __shfl_down(s1, o);
        s2 += __shfl_down(s2, o);
    }
    if ((lane & 31) == 0) {
        const int g = cb * 2 + (lane >> 5);
        atomicAdd(&stats[(n * GROUPS + g) * 2 + 0], s1);
        atomicAdd(&stats[(n * GROUPS + g) * 2 + 1], s2);
    }
}

__global__ __launch_bounds__(256)
void norm_bf16(const unsigned short* __restrict__ yb,
               const float* __restrict__ stats, float* __restrict__ out)
{
    const int total8 = 8 * COUT * SP_OUT / 8;
    const int grp8 = SP_OUT;
    const float inv_cnt = 1.0f / (8.0f * (float)SP_OUT);
    int idx = blockIdx.x * 256 + threadIdx.x;
    const int stride = gridDim.x * 256;
    for (int i = idx; i < total8; i += stride) {
        const int ng = i / grp8;
        const float m1 = stats[ng * 2 + 0] * inv_cnt;
        const float m2 = stats[ng * 2 + 1] * inv_cnt;
        const float rstd = rsqrtf(m2 - m1 * m1 + 1e-5f);
        const uint4 v = ((const uint4*)yb)[i];
        float4 o0, o1;
        o0.x = hswish((__uint_as_float((v.x & 0xffffu) << 16) - m1) * rstd);
        o0.y = hswish((__uint_as_float((v.x >> 16) << 16) - m1) * rstd);
        o0.z = hswish((__uint_as_float((v.y & 0xffffu) << 16) - m1) * rstd);
        o0.w = hswish((__uint_as_float((v.y >> 16) << 16) - m1) * rstd);
        o1.x = hswish((__uint_as_float((v.z & 0xffffu) << 16) - m1) * rstd);
        o1.y = hswish((__uint_as_float((v.z >> 16) << 16) - m1) * rstd);
        o1.z = hswish((__uint_as_float((v.w & 0xffffu) << 16) - m1) * rstd);
        o1.w = hswish((__uint_as_float((v.w >> 16) << 16) - m1) * rstd);
        ((float4*)out)[2 * i + 0] = o0;
        ((float4*)out)[2 * i + 1] = o1;
    }
}

__global__ __launch_bounds__(256)
void norm_hswish(float* __restrict__ y, const float* __restrict__ stats)
{
    const int total4 = (8 * COUT * SP_OUT) / 4;
    const int grp4 = (8 * SP_OUT) / 4;
    const float inv_cnt = 1.0f / (8.0f * (float)SP_OUT);
    float4* p = (float4*)y;
    int idx = blockIdx.x * 256 + threadIdx.x;
    const int stride = gridDim.x * 256;
    for (int i = idx; i < total4; i += stride) {
        const int ng = i / grp4;
        const float m1 = stats[ng * 2 + 0] * inv_cnt;
        const float m2 = stats[ng * 2 + 1] * inv_cnt;
        const float rstd = rsqrtf(m2 - m1 * m1 + 1e-5f);
        float4 v = p[i];
        v.x = hswish((v.x - m1) * rstd);
        v.y = hswish((v.y - m1) * rstd);
        v.z = hswish((v.z - m1) * rstd);
        v.w = hswish((v.w - m1) * rstd);
        p[i] = v;
    }
}

extern "C" void kernel_launch(void* const* d_in, const int* in_sizes, int n_in,
                              void* d_out, int out_size, void* d_ws, size_t ws_size,
                              hipStream_t stream)
{
    const float* x    = (const float*)d_in[0];
    const float* w    = (const float*)d_in[1];
    const float* bias = (const float*)d_in[2];
    float* stats = (float*)d_ws;
    unsigned short* wpk = (unsigned short*)((char*)d_ws + WPK_OFF);

    hipMemsetAsync(d_ws, 0, 512, stream);
    repack_w<<<216, 256, 0, stream>>>(w, wpk);

    dim3 grid(12 * 6, 1, 8);
    const size_t need = (size_t)Y_OFF + (size_t)8 * COUT * SP_OUT * 2;
    if (ws_size >= need) {
        char* ybf = (char*)d_ws + Y_OFF;
        conv_mfma<true><<<grid, 512, 0, stream>>>(x, wpk, bias, ybf, stats);
        norm_bf16<<<2048, 256, 0, stream>>>((const unsigned short*)ybf, stats, (float*)d_out);
    } else {
        conv_mfma<false><<<grid, 512, 0, stream>>>(x, wpk, bias, (char*)d_out, stats);
        norm_hswish<<<2048, 256, 0, stream>>>((float*)d_out, stats);
    }
}

// Round 8
// 163.566 us; speedup vs baseline: 2.6476x; 1.6446x over previous
//
#include <hip/hip_runtime.h>
#include <hip/hip_bf16.h>

typedef __attribute__((ext_vector_type(8))) short bf16x8;
typedef __attribute__((ext_vector_type(4))) float f32x4;

#define DIN 24
#define DOUT 47
#define SPD 2209
#define CIN 32
#define COUT 64
#define SP_IN 13824
#define SP_OUT 103823
#define GROUPS 8
#define WPK_OFF 512
#define Y_OFF 131072
#define LROW 40          // elems per (plane,iw) row: 32 ci + 8 pad (80B, 16B-aligned)
#define PLANE 1000       // 25 rows * LROW (iw 0..23 data, iw=24 zero row)

__device__ __forceinline__ unsigned short f2bf(float v) {
    __hip_bfloat16 h = __float2bfloat16(v);
    return *(const unsigned short*)&h;
}

__device__ __forceinline__ float hswish(float z) {
    float c = fminf(fmaxf(z + 3.f, 0.f), 6.f);
    return z * c * (1.f / 6.f);
}

// wpk[tap][coblk][lane][j]: A-frag bf16, co = coblk*16+(lane&15), ci = (lane>>4)*8+j
__global__ __launch_bounds__(256)
void repack_w(const float* __restrict__ w, unsigned short* __restrict__ wpk)
{
    int i = blockIdx.x * 256 + threadIdx.x;
    if (i >= 27 * 4 * 64 * 8) return;
    int j = i & 7;
    int lane = (i >> 3) & 63;
    int coblk = (i >> 9) & 3;
    int tap = i >> 11;
    int kw = tap % 3, kh = (tap / 3) % 3, kd = tap / 9;
    int co = coblk * 16 + (lane & 15);
    int ci = (lane >> 4) * 8 + j;
    wpk[i] = f2bf(w[(((co * CIN + ci) * 3 + kd) * 3 + kh) * 3 + kw]);
}

#define MFMA16(A, B, C) __builtin_amdgcn_mfma_f32_16x16x32_bf16(A, B, C, 0, 0, 0)

template<bool B16>
__global__ __launch_bounds__(512)
void conv_mfma(const float* __restrict__ x, const unsigned short* __restrict__ wpk,
               const float* __restrict__ bias, char* __restrict__ yb,
               float* __restrict__ stats)
{
    __shared__ unsigned short xs[15 * PLANE];   // 30000 B

    const int bx = blockIdx.x;                  // 12 od-slabs * 6 oh-slabs
    const int t = bx / 6;                       // od slab [4t, 4t+4)
    const int s = bx - t * 6;                   // oh slab [8s, 8s+8)
    const int n = blockIdx.z;
    const int tid = threadIdx.x;

    // ---- stage 15 planes (idl 0..2, ihl 0..4) x 24 iw x 32 ci, fp32->bf16 transpose
    const float* xb = x + (size_t)n * (CIN * SP_IN);
    for (int i = tid; i < 2880; i += 512) {
        int ci = i & 31;
        int rest = i >> 5;                      // 0..89
        int j = rest % 6;
        int pl = rest / 6;                      // 0..14
        int ihl = pl % 5, idl = pl / 5;
        int id = min(2 * t + idl, 23);
        int ih = min(4 * s + ihl, 23);
        const float4 v = *(const float4*)(xb + ci * SP_IN + (id * DIN + ih) * DIN + 4 * j);
        int base = pl * PLANE + (4 * j) * LROW + ci;
        xs[base + 0 * LROW] = f2bf(v.x);
        xs[base + 1 * LROW] = f2bf(v.y);
        xs[base + 2 * LROW] = f2bf(v.z);
        xs[base + 3 * LROW] = f2bf(v.w);
    }
    for (int i = tid; i < 480; i += 512) {      // zero row iw=24 per plane
        xs[(i >> 5) * PLANE + 24 * LROW + (i & 31)] = 0;
    }
    __syncthreads();

    const int lane = tid & 63;
    const int wv = tid >> 6;
    const int cb = wv & 3;                      // co block (16 co)
    const int hh = wv >> 2;                     // oh half (4 rows)
    const int col = lane & 15;
    const int kg = lane >> 4;

    // ---- preload all 27 A-frags once (now actually register-resident) ----
    bf16x8 af[3][3][3];
    #pragma unroll
    for (int kd = 0; kd < 3; ++kd)
        #pragma unroll
        for (int kh = 0; kh < 3; ++kh)
            #pragma unroll
            for (int kw = 0; kw < 3; ++kw) {
                const int tap = (kd * 3 + kh) * 3 + kw;
                af[kd][kh][kw] =
                    *(const bf16x8*)&wpk[(size_t)((tap * 4 + cb) * 64 + lane) * 8];
            }

    // per-lane B row offsets: zero row 24 when (col,kw) parity-invalid
    int off[3][3];
    #pragma unroll
    for (int w = 0; w < 3; ++w)
        #pragma unroll
        for (int kw = 0; kw < 3; ++kw) {
            int num = col + 1 - kw;
            bool pv = ((num & 1) == 0);
            int iw = 8 * w + (num >> 1);
            off[w][kw] = ((pv && iw <= 24) ? iw : 24) * LROW + kg * 8;
        }

    const f32x4 bv = *(const f32x4*)&bias[cb * 16 + kg * 4];
    const size_t cob = ((size_t)n * COUT + cb * 16 + kg * 4) * SP_OUT;
    float s1 = 0.f, s2 = 0.f;

    auto strow = [&](const f32x4 (&A)[3], int od, int oh) {
        const size_t rb = cob + (size_t)od * SPD + (size_t)oh * DOUT;
        #pragma unroll
        for (int w = 0; w < 3; ++w) {
            const int ow = 16 * w + col;
            const bool v = (ow < DOUT);
            #pragma unroll
            for (int j = 0; j < 4; ++j) {
                float val = A[w][j] + bv[j];
                float sw = val / (1.f + __expf(-val));
                if (v) {
                    if (B16)
                        ((unsigned short*)yb)[rb + (size_t)j * SP_OUT + ow] = f2bf(sw);
                    else
                        ((float*)yb)[rb + (size_t)j * SP_OUT + ow] = sw;
                    s1 += sw;
                    s2 += sw * sw;
                }
            }
        }
    };

    #pragma unroll
    for (int e = 0; e < 2; ++e) {
        const int od0 = 4 * t + 2 * e;          // even od, always valid
        const bool odOv = (od0 + 1 < DOUT);
        #pragma unroll
        for (int f = 0; f < 2; ++f) {
            const int bh = 2 * hh + f;
            const int ohE = 8 * s + 2 * bh;     // even oh, always valid
            const int ohO = ohE + 1;
            const bool ohOv = (ohO < DOUT);
            // planes: P00 (kd in {1,2}, kh in {1,2}); P01 (kh=0); P10 (kd=0); P11 (both)
            const int p00 = (e * 5 + bh) * PLANE;
            const int p01 = p00 + PLANE;
            const int p10 = p00 + 5 * PLANE;
            const int p11 = p10 + PLANE;

            f32x4 aEE[3], aEO[3], aOE[3], aOO[3];
            #pragma unroll
            for (int w = 0; w < 3; ++w) {
                aEE[w] = (f32x4){0.f, 0.f, 0.f, 0.f};
                aEO[w] = (f32x4){0.f, 0.f, 0.f, 0.f};
                aOE[w] = (f32x4){0.f, 0.f, 0.f, 0.f};
                aOO[w] = (f32x4){0.f, 0.f, 0.f, 0.f};
            }

            #pragma unroll
            for (int kw = 0; kw < 3; ++kw) {
                #pragma unroll
                for (int w = 0; w < 3; ++w) {
                    const int o = off[w][kw];
                    const bf16x8 b0 = *(const bf16x8*)&xs[p00 + o];
                    aEE[w] = MFMA16(af[1][1][kw], b0, aEE[w]);
                    aEO[w] = MFMA16(af[1][2][kw], b0, aEO[w]);
                    aOE[w] = MFMA16(af[2][1][kw], b0, aOE[w]);
                    aOO[w] = MFMA16(af[2][2][kw], b0, aOO[w]);
                    const bf16x8 b1 = *(const bf16x8*)&xs[p01 + o];
                    aEO[w] = MFMA16(af[1][0][kw], b1, aEO[w]);
                    aOO[w] = MFMA16(af[2][0][kw], b1, aOO[w]);
                    const bf16x8 b2 = *(const bf16x8*)&xs[p10 + o];
                    aOE[w] = MFMA16(af[0][1][kw], b2, aOE[w]);
                    aOO[w] = MFMA16(af[0][2][kw], b2, aOO[w]);
                    const bf16x8 b3 = *(const bf16x8*)&xs[p11 + o];
                    aOO[w] = MFMA16(af[0][0][kw], b3, aOO[w]);
                }
            }

            strow(aEE, od0, ohE);
            if (ohOv) strow(aEO, od0, ohO);
            if (odOv) strow(aOE, od0 + 1, ohE);
            if (odOv && ohOv) strow(aOO, od0 + 1, ohO);
        }
    }

    // stats: lanes 0-31 (kg 0,1) -> group 2cb; lanes 32-63 -> 2cb+1
    #pragma unroll
    for (int o = 16; o; o >>= 1) {
        s1 += __shfl_down(s1, o);
        s2 += __shfl_down(s2, o);
    }
    if ((lane & 31) == 0) {
        const int g = cb * 2 + (lane >> 5);
        atomicAdd(&stats[(n * GROUPS + g) * 2 + 0], s1);
        atomicAdd(&stats[(n * GROUPS + g) * 2 + 1], s2);
    }
}

__global__ __launch_bounds__(256)
void norm_bf16(const unsigned short* __restrict__ yb,
               const float* __restrict__ stats, float* __restrict__ out)
{
    const int total8 = 8 * COUT * SP_OUT / 8;
    const int grp8 = SP_OUT;
    const float inv_cnt = 1.0f / (8.0f * (float)SP_OUT);
    int idx = blockIdx.x * 256 + threadIdx.x;
    const int stride = gridDim.x * 256;
    for (int i = idx; i < total8; i += stride) {
        const int ng = i / grp8;
        const float m1 = stats[ng * 2 + 0] * inv_cnt;
        const float m2 = stats[ng * 2 + 1] * inv_cnt;
        const float rstd = rsqrtf(m2 - m1 * m1 + 1e-5f);
        const uint4 v = ((const uint4*)yb)[i];
        float4 o0, o1;
        o0.x = hswish((__uint_as_float((v.x & 0xffffu) << 16) - m1) * rstd);
        o0.y = hswish((__uint_as_float((v.x >> 16) << 16) - m1) * rstd);
        o0.z = hswish((__uint_as_float((v.y & 0xffffu) << 16) - m1) * rstd);
        o0.w = hswish((__uint_as_float((v.y >> 16) << 16) - m1) * rstd);
        o1.x = hswish((__uint_as_float((v.z & 0xffffu) << 16) - m1) * rstd);
        o1.y = hswish((__uint_as_float((v.z >> 16) << 16) - m1) * rstd);
        o1.z = hswish((__uint_as_float((v.w & 0xffffu) << 16) - m1) * rstd);
        o1.w = hswish((__uint_as_float((v.w >> 16) << 16) - m1) * rstd);
        ((float4*)out)[2 * i + 0] = o0;
        ((float4*)out)[2 * i + 1] = o1;
    }
}

__global__ __launch_bounds__(256)
void norm_hswish(float* __restrict__ y, const float* __restrict__ stats)
{
    const int total4 = (8 * COUT * SP_OUT) / 4;
    const int grp4 = (8 * SP_OUT) / 4;
    const float inv_cnt = 1.0f / (8.0f * (float)SP_OUT);
    float4* p = (float4*)y;
    int idx = blockIdx.x * 256 + threadIdx.x;
    const int stride = gridDim.x * 256;
    for (int i = idx; i < total4; i += stride) {
        const int ng = i / grp4;
        const float m1 = stats[ng * 2 + 0] * inv_cnt;
        const float m2 = stats[ng * 2 + 1] * inv_cnt;
        const float rstd = rsqrtf(m2 - m1 * m1 + 1e-5f);
        float4 v = p[i];
        v.x = hswish((v.x - m1) * rstd);
        v.y = hswish((v.y - m1) * rstd);
        v.z = hswish((v.z - m1) * rstd);
        v.w = hswish((v.w - m1) * rstd);
        p[i] = v;
    }
}

extern "C" void kernel_launch(void* const* d_in, const int* in_sizes, int n_in,
                              void* d_out, int out_size, void* d_ws, size_t ws_size,
                              hipStream_t stream)
{
    const float* x    = (const float*)d_in[0];
    const float* w    = (const float*)d_in[1];
    const float* bias = (const float*)d_in[2];
    float* stats = (float*)d_ws;
    unsigned short* wpk = (unsigned short*)((char*)d_ws + WPK_OFF);

    hipMemsetAsync(d_ws, 0, 512, stream);
    repack_w<<<216, 256, 0, stream>>>(w, wpk);

    dim3 grid(12 * 6, 1, 8);
    const size_t need = (size_t)Y_OFF + (size_t)8 * COUT * SP_OUT * 2;
    if (ws_size >= need) {
        char* ybf = (char*)d_ws + Y_OFF;
        conv_mfma<true><<<grid, 512, 0, stream>>>(x, wpk, bias, ybf, stats);
        norm_bf16<<<2048, 256, 0, stream>>>((const unsigned short*)ybf, stats, (float*)d_out);
    } else {
        conv_mfma<false><<<grid, 512, 0, stream>>>(x, wpk, bias, (char*)d_out, stats);
        norm_hswish<<<2048, 256, 0, stream>>>((float*)d_out, stats);
    }
}

// Round 9
// 162.259 us; speedup vs baseline: 2.6689x; 1.0081x over previous
//
#include <hip/hip_runtime.h>
#include <hip/hip_bf16.h>

typedef __attribute__((ext_vector_type(8))) short bf16x8;
typedef __attribute__((ext_vector_type(4))) float f32x4;

#define DIN 24
#define DOUT 47
#define SPD 2209
#define CIN 32
#define COUT 64
#define SP_IN 13824
#define SP_OUT 103823
#define GROUPS 8
#define WPK_OFF 512
#define Y_OFF 131072
#define LROW 40          // elems per (plane,iw) row: 32 ci + 8 pad (80B, 16B-aligned)
#define PLANE 1000       // 25 rows * LROW (iw 0..23 data, iw=24 zero row)

__device__ __forceinline__ unsigned short f2bf(float v) {
    __hip_bfloat16 h = __float2bfloat16(v);
    return *(const unsigned short*)&h;
}

__device__ __forceinline__ float hswish(float z) {
    float c = fminf(fmaxf(z + 3.f, 0.f), 6.f);
    return z * c * (1.f / 6.f);
}

// wpk[tap][coblk][lane][j]: A-frag bf16, co = coblk*16+(lane&15), ci = (lane>>4)*8+j
__global__ __launch_bounds__(256)
void repack_w(const float* __restrict__ w, unsigned short* __restrict__ wpk)
{
    int i = blockIdx.x * 256 + threadIdx.x;
    if (i >= 27 * 4 * 64 * 8) return;
    int j = i & 7;
    int lane = (i >> 3) & 63;
    int coblk = (i >> 9) & 3;
    int tap = i >> 11;
    int kw = tap % 3, kh = (tap / 3) % 3, kd = tap / 9;
    int co = coblk * 16 + (lane & 15);
    int ci = (lane >> 4) * 8 + j;
    wpk[i] = f2bf(w[(((co * CIN + ci) * 3 + kd) * 3 + kh) * 3 + kw]);
}

#define MFMA16(A, B, C) __builtin_amdgcn_mfma_f32_16x16x32_bf16(A, B, C, 0, 0, 0)

template<bool B16>
__global__ __launch_bounds__(256)
void conv_mfma(const float* __restrict__ x, const unsigned short* __restrict__ wpk,
               const float* __restrict__ bias, char* __restrict__ yb,
               float* __restrict__ stats)
{
    __shared__ unsigned short xs[15 * PLANE];   // 30000 B

    const int bx = blockIdx.x;                  // 12 od-slabs * 6 oh-slabs
    const int t = bx / 6;                       // od slab [4t, 4t+4)
    const int s = bx - t * 6;                   // oh slab [8s, 8s+8)
    const int n = blockIdx.z;
    const int tid = threadIdx.x;

    // ---- stage 15 planes (idl 0..2, ihl 0..4) x 24 iw x 32 ci, fp32->bf16 transpose
    const float* xb = x + (size_t)n * (CIN * SP_IN);
    for (int i = tid; i < 2880; i += 256) {
        int ci = i & 31;
        int rest = i >> 5;                      // 0..89
        int j = rest % 6;
        int pl = rest / 6;                      // 0..14
        int ihl = pl % 5, idl = pl / 5;
        int id = min(2 * t + idl, 23);
        int ih = min(4 * s + ihl, 23);
        const float4 v = *(const float4*)(xb + ci * SP_IN + (id * DIN + ih) * DIN + 4 * j);
        int base = pl * PLANE + (4 * j) * LROW + ci;
        xs[base + 0 * LROW] = f2bf(v.x);
        xs[base + 1 * LROW] = f2bf(v.y);
        xs[base + 2 * LROW] = f2bf(v.z);
        xs[base + 3 * LROW] = f2bf(v.w);
    }
    for (int i = tid; i < 480; i += 256) {      // zero row iw=24 per plane
        xs[(i >> 5) * PLANE + 24 * LROW + (i & 31)] = 0;
    }
    __syncthreads();

    const int lane = tid & 63;
    const int cb = tid >> 6;                    // wave = co block (16 co)
    const int col = lane & 15;
    const int kg = lane >> 4;

    // ---- preload all 27 A-frags once (register-resident) ----
    bf16x8 af[3][3][3];
    #pragma unroll
    for (int kd = 0; kd < 3; ++kd)
        #pragma unroll
        for (int kh = 0; kh < 3; ++kh)
            #pragma unroll
            for (int kw = 0; kw < 3; ++kw) {
                const int tap = (kd * 3 + kh) * 3 + kw;
                af[kd][kh][kw] =
                    *(const bf16x8*)&wpk[(size_t)((tap * 4 + cb) * 64 + lane) * 8];
            }

    // per-lane B row offsets: zero row 24 when (col,kw) parity-invalid
    int off[3][3];
    #pragma unroll
    for (int w = 0; w < 3; ++w)
        #pragma unroll
        for (int kw = 0; kw < 3; ++kw) {
            int num = col + 1 - kw;
            bool pv = ((num & 1) == 0);
            int iw = 8 * w + (num >> 1);
            off[w][kw] = ((pv && iw <= 24) ? iw : 24) * LROW + kg * 8;
        }

    const f32x4 bv = *(const f32x4*)&bias[cb * 16 + kg * 4];
    const size_t cob = ((size_t)n * COUT + cb * 16 + kg * 4) * SP_OUT;
    float s1 = 0.f, s2 = 0.f;

    auto strow = [&](const f32x4 (&A)[3], int od, int oh) {
        const size_t rb = cob + (size_t)od * SPD + (size_t)oh * DOUT;
        #pragma unroll
        for (int w = 0; w < 3; ++w) {
            const int ow = 16 * w + col;
            const bool v = (ow < DOUT);
            #pragma unroll
            for (int j = 0; j < 4; ++j) {
                float val = A[w][j] + bv[j];
                float sw = val / (1.f + __expf(-val));
                if (v) {
                    if (B16)
                        ((unsigned short*)yb)[rb + (size_t)j * SP_OUT + ow] = f2bf(sw);
                    else
                        ((float*)yb)[rb + (size_t)j * SP_OUT + ow] = sw;
                    s1 += sw;
                    s2 += sw * sw;
                }
            }
        }
    };

    #pragma unroll
    for (int e = 0; e < 2; ++e) {
        const int od0 = 4 * t + 2 * e;          // even od, always valid
        const bool odOv = (od0 + 1 < DOUT);
        #pragma unroll
        for (int bh = 0; bh < 4; ++bh) {
            const int ohE = 8 * s + 2 * bh;     // even oh, always valid
            const int ohO = ohE + 1;
            const bool ohOv = (ohO < DOUT);
            // planes: P00 (kd in {1,2}, kh in {1,2}); P01 (kh=0); P10 (kd=0); P11 (both)
            const int p00 = (e * 5 + bh) * PLANE;
            const int p01 = p00 + PLANE;
            const int p10 = p00 + 5 * PLANE;
            const int p11 = p10 + PLANE;

            f32x4 aEE[3], aEO[3], aOE[3], aOO[3];
            #pragma unroll
            for (int w = 0; w < 3; ++w) {
                aEE[w] = (f32x4){0.f, 0.f, 0.f, 0.f};
                aEO[w] = (f32x4){0.f, 0.f, 0.f, 0.f};
                aOE[w] = (f32x4){0.f, 0.f, 0.f, 0.f};
                aOO[w] = (f32x4){0.f, 0.f, 0.f, 0.f};
            }

            #pragma unroll
            for (int kw = 0; kw < 3; ++kw) {
                #pragma unroll
                for (int w = 0; w < 3; ++w) {
                    const int o = off[w][kw];
                    const bf16x8 b0 = *(const bf16x8*)&xs[p00 + o];
                    aEE[w] = MFMA16(af[1][1][kw], b0, aEE[w]);
                    aEO[w] = MFMA16(af[1][2][kw], b0, aEO[w]);
                    aOE[w] = MFMA16(af[2][1][kw], b0, aOE[w]);
                    aOO[w] = MFMA16(af[2][2][kw], b0, aOO[w]);
                    const bf16x8 b1 = *(const bf16x8*)&xs[p01 + o];
                    aEO[w] = MFMA16(af[1][0][kw], b1, aEO[w]);
                    aOO[w] = MFMA16(af[2][0][kw], b1, aOO[w]);
                    const bf16x8 b2 = *(const bf16x8*)&xs[p10 + o];
                    aOE[w] = MFMA16(af[0][1][kw], b2, aOE[w]);
                    aOO[w] = MFMA16(af[0][2][kw], b2, aOO[w]);
                    const bf16x8 b3 = *(const bf16x8*)&xs[p11 + o];
                    aOO[w] = MFMA16(af[0][0][kw], b3, aOO[w]);
                }
            }

            strow(aEE, od0, ohE);
            if (ohOv) strow(aEO, od0, ohO);
            if (odOv) strow(aOE, od0 + 1, ohE);
            if (odOv && ohOv) strow(aOO, od0 + 1, ohO);
        }
    }

    // stats: lanes 0-31 (kg 0,1) -> group 2cb; lanes 32-63 -> 2cb+1
    #pragma unroll
    for (int o = 16; o; o >>= 1) {
        s1 += __shfl_down(s1, o);
        s2 += __shfl_down(s2, o);
    }
    if ((lane & 31) == 0) {
        const int g = cb * 2 + (lane >> 5);
        atomicAdd(&stats[(n * GROUPS + g) * 2 + 0], s1);
        atomicAdd(&stats[(n * GROUPS + g) * 2 + 1], s2);
    }
}

__global__ __launch_bounds__(256)
void norm_bf16(const unsigned short* __restrict__ yb,
               const float* __restrict__ stats, float* __restrict__ out)
{
    const int total8 = 8 * COUT * SP_OUT / 8;
    const int grp8 = SP_OUT;
    const float inv_cnt = 1.0f / (8.0f * (float)SP_OUT);
    int idx = blockIdx.x * 256 + threadIdx.x;
    const int stride = gridDim.x * 256;
    for (int i = idx; i < total8; i += stride) {
        const int ng = i / grp8;
        const float m1 = stats[ng * 2 + 0] * inv_cnt;
        const float m2 = stats[ng * 2 + 1] * inv_cnt;
        const float rstd = rsqrtf(m2 - m1 * m1 + 1e-5f);
        const uint4 v = ((const uint4*)yb)[i];
        float4 o0, o1;
        o0.x = hswish((__uint_as_float((v.x & 0xffffu) << 16) - m1) * rstd);
        o0.y = hswish((__uint_as_float((v.x >> 16) << 16) - m1) * rstd);
        o0.z = hswish((__uint_as_float((v.y & 0xffffu) << 16) - m1) * rstd);
        o0.w = hswish((__uint_as_float((v.y >> 16) << 16) - m1) * rstd);
        o1.x = hswish((__uint_as_float((v.z & 0xffffu) << 16) - m1) * rstd);
        o1.y = hswish((__uint_as_float((v.z >> 16) << 16) - m1) * rstd);
        o1.z = hswish((__uint_as_float((v.w & 0xffffu) << 16) - m1) * rstd);
        o1.w = hswish((__uint_as_float((v.w >> 16) << 16) - m1) * rstd);
        ((float4*)out)[2 * i + 0] = o0;
        ((float4*)out)[2 * i + 1] = o1;
    }
}

__global__ __launch_bounds__(256)
void norm_hswish(float* __restrict__ y, const float* __restrict__ stats)
{
    const int total4 = (8 * COUT * SP_OUT) / 4;
    const int grp4 = (8 * SP_OUT) / 4;
    const float inv_cnt = 1.0f / (8.0f * (float)SP_OUT);
    float4* p = (float4*)y;
    int idx = blockIdx.x * 256 + threadIdx.x;
    const int stride = gridDim.x * 256;
    for (int i = idx; i < total4; i += stride) {
        const int ng = i / grp4;
        const float m1 = stats[ng * 2 + 0] * inv_cnt;
        const float m2 = stats[ng * 2 + 1] * inv_cnt;
        const float rstd = rsqrtf(m2 - m1 * m1 + 1e-5f);
        float4 v = p[i];
        v.x = hswish((v.x - m1) * rstd);
        v.y = hswish((v.y - m1) * rstd);
        v.z = hswish((v.z - m1) * rstd);
        v.w = hswish((v.w - m1) * rstd);
        p[i] = v;
    }
}

extern "C" void kernel_launch(void* const* d_in, const int* in_sizes, int n_in,
                              void* d_out, int out_size, void* d_ws, size_t ws_size,
                              hipStream_t stream)
{
    const float* x    = (const float*)d_in[0];
    const float* w    = (const float*)d_in[1];
    const float* bias = (const float*)d_in[2];
    float* stats = (float*)d_ws;
    unsigned short* wpk = (unsigned short*)((char*)d_ws + WPK_OFF);

    hipMemsetAsync(d_ws, 0, 512, stream);
    repack_w<<<216, 256, 0, stream>>>(w, wpk);

    dim3 grid(12 * 6, 1, 8);
    const size_t need = (size_t)Y_OFF + (size_t)8 * COUT * SP_OUT * 2;
    if (ws_size >= need) {
        char* ybf = (char*)d_ws + Y_OFF;
        conv_mfma<true><<<grid, 256, 0, stream>>>(x, wpk, bias, ybf, stats);
        norm_bf16<<<2048, 256, 0, stream>>>((const unsigned short*)ybf, stats, (float*)d_out);
    } else {
        conv_mfma<false><<<grid, 256, 0, stream>>>(x, wpk, bias, (char*)d_out, stats);
        norm_hswish<<<2048, 256, 0, stream>>>((float*)d_out, stats);
    }
}

// Round 10
// 147.949 us; speedup vs baseline: 2.9271x; 1.0967x over previous
//
#include <hip/hip_runtime.h>
#include <hip/hip_bf16.h>

typedef __attribute__((ext_vector_type(8))) short bf16x8;
typedef __attribute__((ext_vector_type(4))) float f32x4;

#define DIN 24
#define DOUT 47
#define SPD 2209
#define CIN 32
#define COUT 64
#define SP_IN 13824
#define SP_OUT 103823
#define GROUPS 8
#define WPK_OFF 512
#define Y_OFF 131072
#define LROW 40          // elems per (plane,iw) row: 32 ci + 8 pad (80B, 16B-aligned)
#define PLANE 1000       // 25 rows * LROW (iw 0..23 data, iw=24 zero row)

__device__ __forceinline__ unsigned short f2bf(float v) {
    __hip_bfloat16 h = __float2bfloat16(v);
    return *(const unsigned short*)&h;
}

__device__ __forceinline__ float hswish(float z) {
    float c = fminf(fmaxf(z + 3.f, 0.f), 6.f);
    return z * c * (1.f / 6.f);
}

// wpk[tap][coblk][lane][j]: A-frag bf16, co = coblk*16+(lane&15), ci = (lane>>4)*8+j
__global__ __launch_bounds__(256)
void repack_w(const float* __restrict__ w, unsigned short* __restrict__ wpk)
{
    int i = blockIdx.x * 256 + threadIdx.x;
    if (i >= 27 * 4 * 64 * 8) return;
    int j = i & 7;
    int lane = (i >> 3) & 63;
    int coblk = (i >> 9) & 3;
    int tap = i >> 11;
    int kw = tap % 3, kh = (tap / 3) % 3, kd = tap / 9;
    int co = coblk * 16 + (lane & 15);
    int ci = (lane >> 4) * 8 + j;
    wpk[i] = f2bf(w[(((co * CIN + ci) * 3 + kd) * 3 + kh) * 3 + kw]);
}

#define MFMA16(A, B, C) __builtin_amdgcn_mfma_f32_16x16x32_bf16(A, B, C, 0, 0, 0)

template<bool B16>
__global__ __launch_bounds__(256, 3)
void conv_mfma(const float* __restrict__ x, const unsigned short* __restrict__ wpk,
               const float* __restrict__ bias, char* __restrict__ yb,
               float* __restrict__ stats)
{
    __shared__ unsigned short xs[15 * PLANE];   // 30000 B

    const int bx = blockIdx.x;                  // 12 od-slabs * 6 oh-slabs
    const int t = bx / 6;                       // od slab [4t, 4t+4)
    const int s = bx - t * 6;                   // oh slab [8s, 8s+8)
    const int n = blockIdx.z;
    const int tid = threadIdx.x;

    // ---- stage 15 planes (idl 0..2, ihl 0..4) x 24 iw x 32 ci, fp32->bf16 transpose
    const float* xb = x + (size_t)n * (CIN * SP_IN);
    for (int i = tid; i < 2880; i += 256) {
        int ci = i & 31;
        int rest = i >> 5;                      // 0..89
        int j = rest % 6;
        int pl = rest / 6;                      // 0..14
        int ihl = pl % 5, idl = pl / 5;
        int id = min(2 * t + idl, 23);
        int ih = min(4 * s + ihl, 23);
        const float4 v = *(const float4*)(xb + ci * SP_IN + (id * DIN + ih) * DIN + 4 * j);
        int base = pl * PLANE + (4 * j) * LROW + ci;
        xs[base + 0 * LROW] = f2bf(v.x);
        xs[base + 1 * LROW] = f2bf(v.y);
        xs[base + 2 * LROW] = f2bf(v.z);
        xs[base + 3 * LROW] = f2bf(v.w);
    }
    for (int i = tid; i < 480; i += 256) {      // zero row iw=24 per plane
        xs[(i >> 5) * PLANE + 24 * LROW + (i & 31)] = 0;
    }
    __syncthreads();

    const int lane = tid & 63;
    const int cb = tid >> 6;                    // wave = co block (16 co)
    const int col = lane & 15;
    const int kg = lane >> 4;

    // per-kw A-frag base (per-lane): wpk + kw*2048 + cb*512 + lane*8,
    // then af(kd,kh) at +(kd*3+kh)*6144 elements
    const unsigned short* wb = wpk + (size_t)cb * 512 + (size_t)lane * 8;

    const f32x4 bv = *(const f32x4*)&bias[cb * 16 + kg * 4];
    const size_t cob = ((size_t)n * COUT + cb * 16 + kg * 4) * SP_OUT;
    float s1 = 0.f, s2 = 0.f;

    auto strow = [&](const f32x4 (&A)[3], int od, int oh) {
        const size_t rb = cob + (size_t)od * SPD + (size_t)oh * DOUT;
        #pragma unroll
        for (int w = 0; w < 3; ++w) {
            const int ow = 16 * w + col;
            const bool v = (ow < DOUT);
            #pragma unroll
            for (int j = 0; j < 4; ++j) {
                float val = A[w][j] + bv[j];
                float sw = val / (1.f + __expf(-val));
                if (v) {
                    if (B16)
                        ((unsigned short*)yb)[rb + (size_t)j * SP_OUT + ow] = f2bf(sw);
                    else
                        ((float*)yb)[rb + (size_t)j * SP_OUT + ow] = sw;
                    s1 += sw;
                    s2 += sw * sw;
                }
            }
        }
    };

    #pragma unroll
    for (int e = 0; e < 2; ++e) {
        const int od0 = 4 * t + 2 * e;          // even od, always valid
        const bool odOv = (od0 + 1 < DOUT);
        #pragma unroll
        for (int bh = 0; bh < 4; ++bh) {
            const int ohE = 8 * s + 2 * bh;     // even oh, always valid
            const int ohO = ohE + 1;
            const bool ohOv = (ohO < DOUT);
            // planes: P00 (kd in {1,2}, kh in {1,2}); P01 (kh=0); P10 (kd=0); P11 (both)
            const int p00 = (e * 5 + bh) * PLANE;
            const int p01 = p00 + PLANE;
            const int p10 = p00 + 5 * PLANE;
            const int p11 = p10 + PLANE;

            f32x4 aEE[3], aEO[3], aOE[3], aOO[3];
            #pragma unroll
            for (int w = 0; w < 3; ++w) {
                aEE[w] = (f32x4){0.f, 0.f, 0.f, 0.f};
                aEO[w] = (f32x4){0.f, 0.f, 0.f, 0.f};
                aOE[w] = (f32x4){0.f, 0.f, 0.f, 0.f};
                aOO[w] = (f32x4){0.f, 0.f, 0.f, 0.f};
            }

            #pragma unroll 1
            for (int kw = 0; kw < 3; ++kw) {
                // stream this kw's 9 A-frags from L2/L3 (36 VGPR transient)
                const unsigned short* wq = wb + kw * 2048;
                asm volatile("" : "+v"(wq));
                const bf16x8 A00 = *(const bf16x8*)&wq[0 * 6144];
                const bf16x8 A01 = *(const bf16x8*)&wq[1 * 6144];
                const bf16x8 A02 = *(const bf16x8*)&wq[2 * 6144];
                const bf16x8 A10 = *(const bf16x8*)&wq[3 * 6144];
                const bf16x8 A11 = *(const bf16x8*)&wq[4 * 6144];
                const bf16x8 A12 = *(const bf16x8*)&wq[5 * 6144];
                const bf16x8 A20 = *(const bf16x8*)&wq[6 * 6144];
                const bf16x8 A21 = *(const bf16x8*)&wq[7 * 6144];
                const bf16x8 A22 = *(const bf16x8*)&wq[8 * 6144];

                #pragma unroll
                for (int w = 0; w < 3; ++w) {
                    // B row offset for (w, kw): zero row 24 if parity-invalid
                    const int num = col + 1 - kw;
                    const bool pv = ((num & 1) == 0);
                    const int iw = 8 * w + (num >> 1);
                    const int o = ((pv && iw <= 24) ? iw : 24) * LROW + kg * 8;

                    const bf16x8 b0 = *(const bf16x8*)&xs[p00 + o];
                    aEE[w] = MFMA16(A11, b0, aEE[w]);
                    aEO[w] = MFMA16(A12, b0, aEO[w]);
                    aOE[w] = MFMA16(A21, b0, aOE[w]);
                    aOO[w] = MFMA16(A22, b0, aOO[w]);
                    const bf16x8 b1 = *(const bf16x8*)&xs[p01 + o];
                    aEO[w] = MFMA16(A10, b1, aEO[w]);
                    aOO[w] = MFMA16(A20, b1, aOO[w]);
                    const bf16x8 b2 = *(const bf16x8*)&xs[p10 + o];
                    aOE[w] = MFMA16(A01, b2, aOE[w]);
                    aOO[w] = MFMA16(A02, b2, aOO[w]);
                    const bf16x8 b3 = *(const bf16x8*)&xs[p11 + o];
                    aOO[w] = MFMA16(A00, b3, aOO[w]);
                }
            }

            strow(aEE, od0, ohE);
            if (ohOv) strow(aEO, od0, ohO);
            if (odOv) strow(aOE, od0 + 1, ohE);
            if (odOv && ohOv) strow(aOO, od0 + 1, ohO);
        }
    }

    // stats: lanes 0-31 (kg 0,1) -> group 2cb; lanes 32-63 -> 2cb+1
    #pragma unroll
    for (int o = 16; o; o >>= 1) {
        s1 += __shfl_down(s1, o);
        s2 += __shfl_down(s2, o);
    }
    if ((lane & 31) == 0) {
        const int g = cb * 2 + (lane >> 5);
        atomicAdd(&stats[(n * GROUPS + g) * 2 + 0], s1);
        atomicAdd(&stats[(n * GROUPS + g) * 2 + 1], s2);
    }
}

__global__ __launch_bounds__(256)
void norm_bf16(const unsigned short* __restrict__ yb,
               const float* __restrict__ stats, float* __restrict__ out)
{
    const int total8 = 8 * COUT * SP_OUT / 8;
    const int grp8 = SP_OUT;
    const float inv_cnt = 1.0f / (8.0f * (float)SP_OUT);
    int idx = blockIdx.x * 256 + threadIdx.x;
    const int stride = gridDim.x * 256;
    for (int i = idx; i < total8; i += stride) {
        const int ng = i / grp8;
        const float m1 = stats[ng * 2 + 0] * inv_cnt;
        const float m2 = stats[ng * 2 + 1] * inv_cnt;
        const float rstd = rsqrtf(m2 - m1 * m1 + 1e-5f);
        const uint4 v = ((const uint4*)yb)[i];
        float4 o0, o1;
        o0.x = hswish((__uint_as_float((v.x & 0xffffu) << 16) - m1) * rstd);
        o0.y = hswish((__uint_as_float((v.x >> 16) << 16) - m1) * rstd);
        o0.z = hswish((__uint_as_float((v.y & 0xffffu) << 16) - m1) * rstd);
        o0.w = hswish((__uint_as_float((v.y >> 16) << 16) - m1) * rstd);
        o1.x = hswish((__uint_as_float((v.z & 0xffffu) << 16) - m1) * rstd);
        o1.y = hswish((__uint_as_float((v.z >> 16) << 16) - m1) * rstd);
        o1.z = hswish((__uint_as_float((v.w & 0xffffu) << 16) - m1) * rstd);
        o1.w = hswish((__uint_as_float((v.w >> 16) << 16) - m1) * rstd);
        ((float4*)out)[2 * i + 0] = o0;
        ((float4*)out)[2 * i + 1] = o1;
    }
}

__global__ __launch_bounds__(256)
void norm_hswish(float* __restrict__ y, const float* __restrict__ stats)
{
    const int total4 = (8 * COUT * SP_OUT) / 4;
    const int grp4 = (8 * SP_OUT) / 4;
    const float inv_cnt = 1.0f / (8.0f * (float)SP_OUT);
    float4* p = (float4*)y;
    int idx = blockIdx.x * 256 + threadIdx.x;
    const int stride = gridDim.x * 256;
    for (int i = idx; i < total4; i += stride) {
        const int ng = i / grp4;
        const float m1 = stats[ng * 2 + 0] * inv_cnt;
        const float m2 = stats[ng * 2 + 1] * inv_cnt;
        const float rstd = rsqrtf(m2 - m1 * m1 + 1e-5f);
        float4 v = p[i];
        v.x = hswish((v.x - m1) * rstd);
        v.y = hswish((v.y - m1) * rstd);
        v.z = hswish((v.z - m1) * rstd);
        v.w = hswish((v.w - m1) * rstd);
        p[i] = v;
    }
}

extern "C" void kernel_launch(void* const* d_in, const int* in_sizes, int n_in,
                              void* d_out, int out_size, void* d_ws, size_t ws_size,
                              hipStream_t stream)
{
    const float* x    = (const float*)d_in[0];
    const float* w    = (const float*)d_in[1];
    const float* bias = (const float*)d_in[2];
    float* stats = (float*)d_ws;
    unsigned short* wpk = (unsigned short*)((char*)d_ws + WPK_OFF);

    hipMemsetAsync(d_ws, 0, 512, stream);
    repack_w<<<216, 256, 0, stream>>>(w, wpk);

    dim3 grid(12 * 6, 1, 8);
    const size_t need = (size_t)Y_OFF + (size_t)8 * COUT * SP_OUT * 2;
    if (ws_size >= need) {
        char* ybf = (char*)d_ws + Y_OFF;
        conv_mfma<true><<<grid, 256, 0, stream>>>(x, wpk, bias, ybf, stats);
        norm_bf16<<<2048, 256, 0, stream>>>((const unsigned short*)ybf, stats, (float*)d_out);
    } else {
        conv_mfma<false><<<grid, 256, 0, stream>>>(x, wpk, bias, (char*)d_out, stats);
        norm_hswish<<<2048, 256, 0, stream>>>((float*)d_out, stats);
    }
}